// Round 2
// baseline (364.846 us; speedup 1.0000x reference)
//
#include <hip/hip_runtime.h>
#include <hip/hip_bf16.h>
#include <math.h>

#define NEXP  16
#define SEQ   512
#define PRED  720
#define NROWS 8192
#define NFREQ 256

typedef __bf16 bf16x8 __attribute__((ext_vector_type(8)));
typedef float  f32x4  __attribute__((ext_vector_type(4)));

__device__ __forceinline__ void gload_lds16(const void* g, void* l) {
    __builtin_amdgcn_global_load_lds(
        (const __attribute__((address_space(1))) unsigned int*)g,
        (__attribute__((address_space(3))) unsigned int*)l, 16, 0, 0);
}

// ---------------- K0: transpose + fp32->bf16 convert expert weights ----------------
__global__ __launch_bounds__(256) void k_transpose_ew(const float* __restrict__ ew,
                                                      __hip_bfloat16* __restrict__ ewt)
{
    __shared__ float tile[32][33];
    const int e  = blockIdx.z;
    const int p0 = blockIdx.x * 32;
    const int l0 = blockIdx.y * 32;
    const int tx = threadIdx.x & 31;
    const int ty = threadIdx.x >> 5;   // 0..7
    const float* src = ew + (size_t)e * SEQ * PRED;
#pragma unroll
    for (int i = 0; i < 4; ++i) {
        int l = l0 + ty + i * 8;
        int p = p0 + tx;
        tile[ty + i * 8][tx] = (p < PRED) ? src[(size_t)l * PRED + p] : 0.f;
    }
    __syncthreads();
    __hip_bfloat16* dst = ewt + (size_t)e * PRED * SEQ;
#pragma unroll
    for (int i = 0; i < 4; ++i) {
        int p = p0 + ty + i * 8;
        int l = l0 + tx;
        if (p < PRED) dst[(size_t)p * SEQ + l] = __float2bfloat16(tile[tx][ty + i * 8]);
    }
}

// ---------------- K1: per-wave gating (register/shuffle fp64 FFT) --------------------
// One row per wave: 512-pt FFT = 8-pt in-lane DIF x 64-pt cross-lane DIF (shfl_xor).
__global__ __launch_bounds__(256) void k_gate(const float* __restrict__ x,
                                              const float* __restrict__ gw,
                                              const float* __restrict__ gb,
                                              __hip_bfloat16* __restrict__ xn,
                                              float* __restrict__ meta,
                                              int* __restrict__ eidx,
                                              int* __restrict__ counts)
{
    __shared__ double Pw[4][256];
    __shared__ double Gs[4][16];

    const int t  = threadIdx.x;
    const int wv = t >> 6, l = t & 63;
    const int b  = blockIdx.x * 4 + wv;
    const float* xr = x + (size_t)b * SEQ;

    // load 8 samples: v[t1] = x[64*t1 + l]; accumulate mean/sumsq in fp64
    double vr[8], vi[8];
    double s1 = 0.0, s2 = 0.0;
#pragma unroll
    for (int t1 = 0; t1 < 8; ++t1) {
        double xv = (double)xr[64 * t1 + l];
        vr[t1] = xv; s1 += xv; s2 += xv * xv;
    }
#pragma unroll
    for (int off = 1; off < 64; off <<= 1) {
        s1 += __shfl_xor(s1, off);
        s2 += __shfl_xor(s2, off);
    }
    const double mu = s1 * (1.0 / 512.0);
    double var = s2 * (1.0 / 512.0) - mu * mu;
    if (var < 0.0) var = 0.0;
    const double sd = sqrt(var) + 1e-5, inv = 1.0 / sd;

#pragma unroll
    for (int t1 = 0; t1 < 8; ++t1) {
        vr[t1] -= mu;
        vi[t1]  = 0.0;
        xn[(size_t)b * SEQ + 64 * t1 + l] = __float2bfloat16((float)(vr[t1] * inv));
    }

    // ---- in-lane 8-pt DIF FFT over t1 (output slot p holds X8[br3(p)]) ----
    {
        const double C = 0.70710678118654752440084436210485;
        double a0 = vr[0] + vr[4], a1 = vr[1] + vr[5], a2 = vr[2] + vr[6], a3 = vr[3] + vr[7];
        double d0 = vr[0] - vr[4], d1 = vr[1] - vr[5], d2 = vr[2] - vr[6], d3 = vr[3] - vr[7];
        double c0 = a0 + a2, c2 = a0 - a2, c1 = a1 + a3;
        double c3i = a3 - a1;                     // c3 = (a1-a3)*(-i) => (0, a3-a1)
        double e1r = C * (d1 - d3), e1i = -C * (d1 + d3);
        vr[0] = c0 + c1;            vi[0] = 0.0;          // X0
        vr[1] = c0 - c1;            vi[1] = 0.0;          // X4
        vr[2] = c2;                 vi[2] = c3i;          // X2
        vr[3] = c2;                 vi[3] = -c3i;         // X6
        vr[4] = d0 + e1r;           vi[4] = -d2 + e1i;    // X1
        vr[5] = d0 - e1r;           vi[5] = -d2 - e1i;    // X5
        vr[6] = d0 - e1r;           vi[6] =  d2 + e1i;    // X3  (e2=(d0,d2), e3=(-e1r, e1i))
        vr[7] = d0 + e1r;           vi[7] =  d2 - e1i;    // X7
    }

    // ---- twiddle: slot p *= w^{br3(p)}, w = exp(-2*pi*i*l/512) ----
    double w1r, w1i;
    {
        double sv, cv;
        sincos((double)l * (-6.283185307179586476925286766559 / 512.0), &sv, &cv);
        w1r = cv; w1i = sv;
    }
    {
        double wkr = w1r, wki = w1i;
#define TWID(sl) { double tr_ = vr[sl]*wkr - vi[sl]*wki; vi[sl] = vr[sl]*wki + vi[sl]*wkr; vr[sl] = tr_; }
#define WSTEP()  { double nr_ = wkr*w1r - wki*w1i; wki = wkr*w1i + wki*w1r; wkr = nr_; }
        TWID(4) WSTEP() TWID(2) WSTEP() TWID(6) WSTEP() TWID(1)
        WSTEP() TWID(5) WSTEP() TWID(3) WSTEP() TWID(7)
#undef TWID
#undef WSTEP
    }

    // ---- cross-lane 64-pt DIF FFT via shfl_xor; twiddles from W = w^8 ----
    double twr, twi;
    {
        double w2r = w1r * w1r - w1i * w1i, w2i = 2.0 * w1r * w1i;
        double w4r = w2r * w2r - w2i * w2i, w4i = 2.0 * w2r * w2i;
        twr = w4r * w4r - w4i * w4i; twi = 2.0 * w4r * w4i;   // W = w^8
    }
#pragma unroll
    for (int st = 0; st < 6; ++st) {
        const int h = 32 >> st;
        const bool hi = (l & h) != 0;
        const double ter = hi ? twr : 1.0;
        const double tei = hi ? twi : 0.0;
#pragma unroll
        for (int p = 0; p < 8; ++p) {
            double br_ = __shfl_xor(vr[p], h);
            double bi_ = __shfl_xor(vi[p], h);
            double dr = hi ? (vr[p] - br_) : (vr[p] + br_);
            double di = hi ? (vi[p] - bi_) : (vi[p] + bi_);
            vr[p] = dr * ter - di * tei;
            vi[p] = dr * tei + di * ter;
        }
        double nr_ = twr * twr - twi * twi;
        twi = 2.0 * twr * twi; twr = nr_;
    }

    // ---- power spectrum: k = br3(p) + 8*br6(l); k<256 <=> l even ----
    const int k2 = (int)(__brev((unsigned)l) >> 26);
    double ps = 0.0;
    if ((l & 1) == 0) {
        constexpr int BR3[8] = {0, 4, 2, 6, 1, 5, 3, 7};
#pragma unroll
        for (int p = 0; p < 8; ++p) {
            double P = vr[p] * vr[p] + vi[p] * vi[p];
            ps += P;
            Pw[wv][BR3[p] + 8 * k2] = P;
        }
    }
#pragma unroll
    for (int off = 1; off < 64; off <<= 1) ps += __shfl_xor(ps, off);
    __syncthreads();

    // ---- gate dot: expert e = l>>2, k = (l&3) + 4j ----
    {
        const int e = l >> 2, kb = l & 3;
        double acc = 0.0;
#pragma unroll 8
        for (int j = 0; j < 64; ++j) {
            int k = kb + 4 * j;
            acc += Pw[wv][k] * (double)gw[e * NFREQ + k];
        }
        acc += __shfl_xor(acc, 1);
        acc += __shfl_xor(acc, 2);
        if (kb == 0) Gs[wv][e] = acc;
    }
    __syncthreads();

    if (l == 0) {
        const double sdiv  = (ps == 0.0) ? 1.0 : ps;
        const double inv_s = 1.0 / sdiv;
        double best = -1e300, best2 = -1e300;
        int i0b = 0, i1b = 0;
#pragma unroll
        for (int i = 0; i < NEXP; ++i) {
            double v = Gs[wv][i] * inv_s + (double)gb[i];
            if (v > best)       { best2 = best; i1b = i0b; best = v; i0b = i; }
            else if (v > best2) { best2 = v; i1b = i; }
        }
        const double eexp = exp(best2 - best);
        const double w0 = 1.0 / (1.0 + eexp);
        const double w1 = eexp / (1.0 + eexp);
        meta[b * 4 + 0] = (float)mu;
        meta[b * 4 + 1] = (float)(w0 * sd);
        meta[b * 4 + 2] = (float)(w1 * sd);
        meta[b * 4 + 3] = (float)sd;
        eidx[b * 2 + 0] = i0b;
        eidx[b * 2 + 1] = i1b;
        atomicAdd(&counts[i0b], 1);
        atomicAdd(&counts[NEXP + i1b], 1);
    }
}

// ---------------- K2: exclusive scan of 2x16 counts -> offsets, init cursors ---------
__global__ void k_scan(const int* __restrict__ counts, int* __restrict__ offs,
                       int* __restrict__ cursors)
{
    const int t = threadIdx.x;
    if (t < 2) {
        int base = t * NEXP, acc = 0;
        for (int i = 0; i < NEXP; ++i) {
            offs[base + i]    = acc;
            cursors[base + i] = acc;
            acc += counts[base + i];
        }
    }
}

// ---------------- K3: scatter row ids into per-(slot,expert) lists -------------------
__global__ __launch_bounds__(256) void k_scatter(const int* __restrict__ eidx,
                                                 int* __restrict__ cursors,
                                                 int* __restrict__ lists)
{
    const int b = blockIdx.x * 256 + threadIdx.x;
    if (b >= NROWS) return;
    const int e0 = eidx[2 * b];
    const int e1 = eidx[2 * b + 1];
    const int p0 = atomicAdd(&cursors[e0], 1);
    lists[p0] = b;
    const int p1 = atomicAdd(&cursors[NEXP + e1], 1);
    lists[NROWS + p1] = b;
}

// ---------------- K4/K5: grouped gather-GEMM, 128x240 tile, BK=64, gld_lds -----------
// Flat grid 3072 = 8 XCD * 2 experts * 64 rowtiles * 3 ctiles; bid%8 pins expert pair
// to one XCD for L2 reuse of A and B.
template <int SLOT>
__global__ __launch_bounds__(256) void k_expert_gemm(
    const __hip_bfloat16* __restrict__ xn, const __hip_bfloat16* __restrict__ ewt,
    const float* __restrict__ eb, const float* __restrict__ meta,
    const int* __restrict__ lists, const int* __restrict__ offs,
    const int* __restrict__ counts, float* __restrict__ out)
{
    const int bid = blockIdx.x;
    const int xcd = bid & 7;
    const int s   = bid >> 3;                     // 0..383
    const int hi_ = (s >= 192) ? 1 : 0;
    const int e   = (xcd << 1) + hi_;
    const int rem = s - hi_ * 192;                // 0..191
    const int rt  = rem / 3;
    const int ct  = rem % 3;
    const int n_e = counts[SLOT * NEXP + e];
    if (rt * 128 >= n_e) return;

    __shared__ __align__(16) __hip_bfloat16 As[128][64];
    __shared__ __align__(16) __hip_bfloat16 Bs[256][64];
    __shared__ int   rowB[128];
    __shared__ float rowMu[128];
    __shared__ float rowC[128];

    const int t  = threadIdx.x;
    const int wv = t >> 6, l = t & 63;
    const int* list = lists + SLOT * NROWS + offs[SLOT * NEXP + e];
    if (t < 128) {
        int r  = rt * 128 + t;
        int bb = (r < n_e) ? list[r] : -1;
        rowB[t] = bb;
        rowMu[t] = (bb >= 0) ? meta[bb * 4] : 0.f;
        rowC[t]  = (bb >= 0) ? meta[bb * 4 + 1 + SLOT] : 0.f;
    }
    __syncthreads();

    // per-lane gld sources; source chunk pre-swizzled: kc = (l&7) ^ (row&7)
    const __hip_bfloat16* asrc[4];
#pragma unroll
    for (int i = 0; i < 4; ++i) {
        int row = wv * 32 + i * 8 + (l >> 3);
        int ab  = rowB[row];
        int kc  = (l & 7) ^ (row & 7);
        asrc[i] = xn + ((ab >= 0) ? (size_t)ab * SEQ : 0) + kc * 8;
    }
    const __hip_bfloat16* bsrc[8];
#pragma unroll
    for (int i = 0; i < 8; ++i) {
        int col  = wv * 64 + i * 8 + (l >> 3);    // LDS col 0..255
        int colc = (col < 240) ? col : 239;       // clamp source (pad cols unused)
        int kc   = (l & 7) ^ (col & 7);
        bsrc[i] = ewt + ((size_t)e * PRED + (size_t)ct * 240 + colc) * SEQ + kc * 8;
    }

    f32x4 acc[2][15];
#pragma unroll
    for (int m = 0; m < 2; ++m)
#pragma unroll
        for (int c = 0; c < 15; ++c) acc[m][c] = f32x4{0.f, 0.f, 0.f, 0.f};

    const int fr = l & 15, fq = l >> 4;

    for (int kt = 0; kt < 8; ++kt) {
        const int koff = kt * 64;
#pragma unroll
        for (int i = 0; i < 4; ++i)
            gload_lds16(asrc[i] + koff, &As[wv * 32 + i * 8][0]);
#pragma unroll
        for (int i = 0; i < 8; ++i)
            gload_lds16(bsrc[i] + koff, &Bs[wv * 64 + i * 8][0]);
        __syncthreads();

#pragma unroll
        for (int kh = 0; kh < 2; ++kh) {
            const int x8 = (((kh * 4 + fq) ^ (fr & 7)) * 8);
            const bf16x8 af0 = *(const bf16x8*)&As[wv * 32 + fr][x8];
            const bf16x8 af1 = *(const bf16x8*)&As[wv * 32 + 16 + fr][x8];
#pragma unroll
            for (int c = 0; c < 15; ++c) {
                const bf16x8 bf = *(const bf16x8*)&Bs[c * 16 + fr][x8];
                acc[0][c] = __builtin_amdgcn_mfma_f32_16x16x32_bf16(af0, bf, acc[0][c], 0, 0, 0);
                acc[1][c] = __builtin_amdgcn_mfma_f32_16x16x32_bf16(af1, bf, acc[1][c], 0, 0, 0);
            }
        }
        __syncthreads();
    }

    // epilogue: D row = fq*4 + r, col = fr
#pragma unroll
    for (int c = 0; c < 15; ++c) {
        const int col = ct * 240 + c * 16 + fr;
        const float ebv = eb[e * PRED + col];
#pragma unroll
        for (int mf = 0; mf < 2; ++mf) {
#pragma unroll
            for (int r = 0; r < 4; ++r) {
                const int rl = wv * 32 + mf * 16 + fq * 4 + r;
                const int bb = rowB[rl];
                if (bb < 0) continue;
                const float v = acc[mf][c][r] + ebv;
                float* op = out + (size_t)bb * PRED + col;
                if (SLOT == 0) *op = rowMu[rl] + rowC[rl] * v;
                else           *op += rowC[rl] * v;
            }
        }
    }
}

// -------------------------------- launch ---------------------------------------------
extern "C" void kernel_launch(void* const* d_in, const int* in_sizes, int n_in,
                              void* d_out, int out_size, void* d_ws, size_t ws_size,
                              hipStream_t stream)
{
    const float* x  = (const float*)d_in[0];
    const float* gw = (const float*)d_in[1];
    const float* gb = (const float*)d_in[2];
    const float* ew = (const float*)d_in[3];
    const float* eb = (const float*)d_in[4];
    float* out = (float*)d_out;
    char*  ws  = (char*)d_ws;

    constexpr size_t XN_OFF   = 0;
    constexpr size_t XN_SZ    = (size_t)NROWS * SEQ * 2;
    constexpr size_t EWT_OFF  = XN_OFF + XN_SZ;
    constexpr size_t EWT_SZ   = (size_t)NEXP * PRED * SEQ * 2;
    constexpr size_t META_OFF = EWT_OFF + EWT_SZ;
    constexpr size_t META_SZ  = (size_t)NROWS * 4 * 4;
    constexpr size_t EIDX_OFF = META_OFF + META_SZ;
    constexpr size_t EIDX_SZ  = (size_t)NROWS * 2 * 4;
    constexpr size_t LIST_OFF = EIDX_OFF + EIDX_SZ;
    constexpr size_t LIST_SZ  = (size_t)2 * NROWS * 4;
    constexpr size_t CNT_OFF  = LIST_OFF + LIST_SZ;
    constexpr size_t OFFS_OFF = CNT_OFF + 128;
    constexpr size_t CURS_OFF = OFFS_OFF + 128;

    __hip_bfloat16* xn  = (__hip_bfloat16*)(ws + XN_OFF);
    __hip_bfloat16* ewt = (__hip_bfloat16*)(ws + EWT_OFF);
    float* meta  = (float*)(ws + META_OFF);
    int* eidx    = (int*)(ws + EIDX_OFF);
    int* lists   = (int*)(ws + LIST_OFF);
    int* counts  = (int*)(ws + CNT_OFF);
    int* offs    = (int*)(ws + OFFS_OFF);
    int* cursors = (int*)(ws + CURS_OFF);

    hipMemsetAsync(counts, 0, 128, stream);

    k_transpose_ew<<<dim3(23, 16, NEXP), dim3(256), 0, stream>>>(ew, ewt);
    k_gate<<<dim3(NROWS / 4), dim3(256), 0, stream>>>(x, gw, gb, xn, meta, eidx, counts);
    k_scan<<<dim3(1), dim3(64), 0, stream>>>(counts, offs, cursors);
    k_scatter<<<dim3(NROWS / 256), dim3(256), 0, stream>>>(eidx, cursors, lists);
    k_expert_gemm<0><<<dim3(3072), dim3(256), 0, stream>>>(
        xn, ewt, eb, meta, lists, offs, counts, out);
    k_expert_gemm<1><<<dim3(3072), dim3(256), 0, stream>>>(
        xn, ewt, eb, meta, lists, offs, counts, out);
}

// Round 3
// 262.254 us; speedup vs baseline: 1.3912x; 1.3912x over previous
//
#include <hip/hip_runtime.h>
#include <hip/hip_bf16.h>
#include <math.h>

#define NEXP  16
#define SEQ   512
#define PRED  720
#define NROWS 8192
#define NFREQ 256

typedef __bf16 bf16x8 __attribute__((ext_vector_type(8)));
typedef float  f32x16 __attribute__((ext_vector_type(16)));

__device__ __forceinline__ void gload_lds16(const void* g, void* l) {
    __builtin_amdgcn_global_load_lds(
        (const __attribute__((address_space(1))) unsigned int*)g,
        (__attribute__((address_space(3))) unsigned int*)l, 16, 0, 0);
}

// ---------------- K0: transpose + fp32->bf16 convert expert weights ----------------
__global__ __launch_bounds__(256) void k_transpose_ew(const float* __restrict__ ew,
                                                      __hip_bfloat16* __restrict__ ewt)
{
    __shared__ float tile[32][33];
    const int e  = blockIdx.z;
    const int p0 = blockIdx.x * 32;
    const int l0 = blockIdx.y * 32;
    const int tx = threadIdx.x & 31;
    const int ty = threadIdx.x >> 5;   // 0..7
    const float* src = ew + (size_t)e * SEQ * PRED;
#pragma unroll
    for (int i = 0; i < 4; ++i) {
        int l = l0 + ty + i * 8;
        int p = p0 + tx;
        tile[ty + i * 8][tx] = (p < PRED) ? src[(size_t)l * PRED + p] : 0.f;
    }
    __syncthreads();
    __hip_bfloat16* dst = ewt + (size_t)e * PRED * SEQ;
#pragma unroll
    for (int i = 0; i < 4; ++i) {
        int p = p0 + ty + i * 8;
        int l = l0 + tx;
        if (p < PRED) dst[(size_t)p * SEQ + l] = __float2bfloat16(tile[tx][ty + i * 8]);
    }
}

// ---------------- K1: per-wave gating (register/shuffle fp64 FFT, no libcalls) -------
__global__ __launch_bounds__(256, 4) void k_gate(const float* __restrict__ x,
                                                 const float* __restrict__ gw,
                                                 const float* __restrict__ gb,
                                                 __hip_bfloat16* __restrict__ xn,
                                                 float* __restrict__ meta,
                                                 int* __restrict__ eidx,
                                                 int* __restrict__ counts)
{
    __shared__ double Pw[4][256];
    __shared__ double Gs[4][16];

    const int t  = threadIdx.x;
    const int wv = t >> 6, l = t & 63;
    const int b  = blockIdx.x * 4 + wv;
    const float* xr = x + (size_t)b * SEQ;

    // load 8 samples: v[t1] = x[64*t1 + l]; accumulate mean/sumsq in fp64
    double vr[8], vi[8];
    double s1 = 0.0, s2 = 0.0;
#pragma unroll
    for (int t1 = 0; t1 < 8; ++t1) {
        double xv = (double)xr[64 * t1 + l];
        vr[t1] = xv; s1 += xv; s2 += xv * xv;
    }
#pragma unroll
    for (int off = 1; off < 64; off <<= 1) {
        s1 += __shfl_xor(s1, off);
        s2 += __shfl_xor(s2, off);
    }
    const double mu = s1 * (1.0 / 512.0);
    double var = s2 * (1.0 / 512.0) - mu * mu;
    if (var < 0.0) var = 0.0;
    const double sd = sqrt(var) + 1e-5, inv = 1.0 / sd;

#pragma unroll
    for (int t1 = 0; t1 < 8; ++t1) {
        vr[t1] -= mu;
        vi[t1]  = 0.0;
        xn[(size_t)b * SEQ + 64 * t1 + l] = __float2bfloat16((float)(vr[t1] * inv));
    }

    // ---- in-lane 8-pt DIF FFT over t1 (output slot p holds X8[br3(p)]) ----
    {
        const double C = 0.70710678118654752440084436210485;
        double a0 = vr[0] + vr[4], a1 = vr[1] + vr[5], a2 = vr[2] + vr[6], a3 = vr[3] + vr[7];
        double d0 = vr[0] - vr[4], d1 = vr[1] - vr[5], d2 = vr[2] - vr[6], d3 = vr[3] - vr[7];
        double c0 = a0 + a2, c2 = a0 - a2, c1 = a1 + a3;
        double c3i = a3 - a1;
        double e1r = C * (d1 - d3), e1i = -C * (d1 + d3);
        vr[0] = c0 + c1;            vi[0] = 0.0;
        vr[1] = c0 - c1;            vi[1] = 0.0;
        vr[2] = c2;                 vi[2] = c3i;
        vr[3] = c2;                 vi[3] = -c3i;
        vr[4] = d0 + e1r;           vi[4] = -d2 + e1i;
        vr[5] = d0 - e1r;           vi[5] = -d2 - e1i;
        vr[6] = d0 - e1r;           vi[6] =  d2 + e1i;
        vr[7] = d0 + e1r;           vi[7] =  d2 - e1i;
    }

    // ---- w = exp(-2*pi*i*l/512) via binary decomposition (NO sincos libcall) ----
    double w1r = 1.0, w1i = 0.0;
    {
        constexpr double Cr[6] = {0.9999247018391445033, 0.9996988186962042201,
                                  0.9987954562051723927, 0.9951847266721968862,
                                  0.9807852804032304491, 0.9238795325112867561};
        constexpr double Ci[6] = {-0.0122715382857199261, -0.0245412285229122880,
                                  -0.0490676743274180143, -0.0980171403295606020,
                                  -0.1950903220161282678, -0.3826834323650897717};
#pragma unroll
        for (int j = 0; j < 6; ++j) {
            const bool on = (l >> j) & 1;
            const double mr = on ? Cr[j] : 1.0;
            const double mi = on ? Ci[j] : 0.0;
            const double nr = w1r * mr - w1i * mi;
            w1i = w1r * mi + w1i * mr;
            w1r = nr;
        }
    }

    // ---- twiddle: slot p *= w^{br3(p)} ----
    {
        double wkr = w1r, wki = w1i;
#define TWID(sl) { double tr_ = vr[sl]*wkr - vi[sl]*wki; vi[sl] = vr[sl]*wki + vi[sl]*wkr; vr[sl] = tr_; }
#define WSTEP()  { double nr_ = wkr*w1r - wki*w1i; wki = wkr*w1i + wki*w1r; wkr = nr_; }
        TWID(4) WSTEP() TWID(2) WSTEP() TWID(6) WSTEP() TWID(1)
        WSTEP() TWID(5) WSTEP() TWID(3) WSTEP() TWID(7)
#undef TWID
#undef WSTEP
    }

    // ---- cross-lane 64-pt DIF FFT via shfl_xor; twiddles from W = w^8 ----
    double twr, twi;
    {
        double w2r = w1r * w1r - w1i * w1i, w2i = 2.0 * w1r * w1i;
        double w4r = w2r * w2r - w2i * w2i, w4i = 2.0 * w2r * w2i;
        twr = w4r * w4r - w4i * w4i; twi = 2.0 * w4r * w4i;   // W = w^8
    }
#pragma unroll
    for (int st = 0; st < 6; ++st) {
        const int h = 32 >> st;
        const bool hi = (l & h) != 0;
        const double ter = hi ? twr : 1.0;
        const double tei = hi ? twi : 0.0;
#pragma unroll
        for (int p = 0; p < 8; ++p) {
            double br_ = __shfl_xor(vr[p], h);
            double bi_ = __shfl_xor(vi[p], h);
            double dr = hi ? (vr[p] - br_) : (vr[p] + br_);
            double di = hi ? (vi[p] - bi_) : (vi[p] + bi_);
            vr[p] = dr * ter - di * tei;
            vi[p] = dr * tei + di * ter;
        }
        double nr_ = twr * twr - twi * twi;
        twi = 2.0 * twr * twi; twr = nr_;
    }

    // ---- power spectrum: k = br3(p) + 8*br6(l); k<256 <=> l even ----
    const int k2 = (int)(__brev((unsigned)l) >> 26);
    double ps = 0.0;
    if ((l & 1) == 0) {
        constexpr int BR3[8] = {0, 4, 2, 6, 1, 5, 3, 7};
#pragma unroll
        for (int p = 0; p < 8; ++p) {
            double P = vr[p] * vr[p] + vi[p] * vi[p];
            ps += P;
            Pw[wv][BR3[p] + 8 * k2] = P;
        }
    }
#pragma unroll
    for (int off = 1; off < 64; off <<= 1) ps += __shfl_xor(ps, off);
    __syncthreads();

    // ---- gate dot: expert e = l>>2, k = (l&3) + 4j ----
    {
        const int e = l >> 2, kb = l & 3;
        double acc = 0.0;
#pragma unroll 8
        for (int j = 0; j < 64; ++j) {
            int k = kb + 4 * j;
            acc += Pw[wv][k] * (double)gw[e * NFREQ + k];
        }
        acc += __shfl_xor(acc, 1);
        acc += __shfl_xor(acc, 2);
        if (kb == 0) Gs[wv][e] = acc;
    }
    __syncthreads();

    if (l == 0) {
        const double sdiv  = (ps == 0.0) ? 1.0 : ps;
        const double inv_s = 1.0 / sdiv;
        double best = -1e300, best2 = -1e300;
        int i0b = 0, i1b = 0;
#pragma unroll
        for (int i = 0; i < NEXP; ++i) {
            double v = Gs[wv][i] * inv_s + (double)gb[i];
            if (v > best)       { best2 = best; i1b = i0b; best = v; i0b = i; }
            else if (v > best2) { best2 = v; i1b = i; }
        }
        const double eexp = (double)__expf((float)(best2 - best));
        const double w0 = 1.0 / (1.0 + eexp);
        const double w1 = eexp / (1.0 + eexp);
        meta[b * 4 + 0] = (float)mu;
        meta[b * 4 + 1] = (float)(w0 * sd);
        meta[b * 4 + 2] = (float)(w1 * sd);
        meta[b * 4 + 3] = (float)sd;
        eidx[b * 2 + 0] = i0b;
        eidx[b * 2 + 1] = i1b;
        atomicAdd(&counts[i0b], 1);
        atomicAdd(&counts[NEXP + i1b], 1);
    }
}

// ---------------- K2: scan counts -> row offsets, cursors, tile offsets --------------
__global__ void k_scan(const int* __restrict__ counts, int* __restrict__ offs,
                       int* __restrict__ cursors, int* __restrict__ toff)
{
    const int t = threadIdx.x;
    if (t < 2) {
        int base = t * NEXP, acc = 0, tac = 0;
        for (int i = 0; i < NEXP; ++i) {
            int c = counts[base + i];
            offs[base + i]    = acc;
            cursors[base + i] = acc;
            acc += c;
            toff[t * 17 + i] = tac;
            tac += (c + 127) >> 7;
        }
        toff[t * 17 + 16] = tac;
    }
}

// ---------------- K3: scatter row ids into per-(slot,expert) lists -------------------
__global__ __launch_bounds__(256) void k_scatter(const int* __restrict__ eidx,
                                                 int* __restrict__ cursors,
                                                 int* __restrict__ lists)
{
    const int b = blockIdx.x * 256 + threadIdx.x;
    if (b >= NROWS) return;
    const int e0 = eidx[2 * b];
    const int e1 = eidx[2 * b + 1];
    const int p0 = atomicAdd(&cursors[e0], 1);
    lists[p0] = b;
    const int p1 = atomicAdd(&cursors[NEXP + e1], 1);
    lists[NROWS + p1] = b;
}

// ---------------- K4/K5: grouped gather-GEMM, 128x128 tile, 32x32x16 MFMA ------------
// grid (6 ctiles, 80 tile-slots); block maps tile-slot -> (expert, rowtile) via toff.
template <int SLOT>
__global__ __launch_bounds__(256, 2) void k_expert_gemm(
    const __hip_bfloat16* __restrict__ xn, const __hip_bfloat16* __restrict__ ewt,
    const float* __restrict__ eb, const float* __restrict__ meta,
    const int* __restrict__ lists, const int* __restrict__ offs,
    const int* __restrict__ counts, const int* __restrict__ toff,
    float* __restrict__ out)
{
    const int tid = blockIdx.y;
    if (tid >= toff[SLOT * 17 + 16]) return;
    int e = 0;
#pragma unroll
    for (int i = 0; i < 15; ++i) e += (toff[SLOT * 17 + e + 1] <= tid) ? 1 : 0;
    const int rt  = tid - toff[SLOT * 17 + e];
    const int ct  = blockIdx.x;                   // 0..5
    const int n_e = counts[SLOT * NEXP + e];

    __shared__ __align__(16) __hip_bfloat16 As[2][128][64];
    __shared__ __align__(16) __hip_bfloat16 Bs[2][128][64];
    __shared__ int   rowB[128];
    __shared__ float rowMu[128];
    __shared__ float rowC[128];

    const int t  = threadIdx.x;
    const int wv = t >> 6, l = t & 63;
    const int* list = lists + SLOT * NROWS + offs[SLOT * NEXP + e];
    if (t < 128) {
        int r  = rt * 128 + t;
        int bb = (r < n_e) ? list[r] : -1;
        rowB[t]  = bb;
        rowMu[t] = (bb >= 0) ? meta[bb * 4] : 0.f;
        rowC[t]  = (bb >= 0) ? meta[bb * 4 + 1 + SLOT] : 0.f;
    }
    __syncthreads();

    // staging sources: per K-step each thread issues 4 A + 4 B gld_lds (16B each).
    // LDS dest is linear (base + lane*16); bank swizzle folded into the GLOBAL source
    // chunk: swz(r) = (r&7) ^ ((r&8)>>1).
    const int srow = l >> 3;           // 0..7
    const int schk = l & 7;
    const __hip_bfloat16* asrc[4];
    const __hip_bfloat16* bsrc[4];
#pragma unroll
    for (int i = 0; i < 4; ++i) {
        const int r   = wv * 32 + i * 8 + srow;
        const int swz = (r & 7) ^ ((r & 8) >> 1);
        const int ab  = rowB[r];
        asrc[i] = xn + ((ab >= 0) ? (size_t)ab * SEQ : 0) + (size_t)(schk ^ swz) * 8;
        const int gc  = ct * 128 + r;
        const int gcc = (gc < PRED) ? gc : (PRED - 1);
        bsrc[i] = ewt + ((size_t)e * PRED + gcc) * SEQ + (size_t)(schk ^ swz) * 8;
    }

#define STAGE(buf, koff) do {                                              \
    _Pragma("unroll")                                                      \
    for (int i_ = 0; i_ < 4; ++i_)                                         \
        gload_lds16(asrc[i_] + (koff), &As[buf][wv * 32 + i_ * 8][0]);     \
    _Pragma("unroll")                                                      \
    for (int i_ = 0; i_ < 4; ++i_)                                         \
        gload_lds16(bsrc[i_] + (koff), &Bs[buf][wv * 32 + i_ * 8][0]);     \
} while (0)

    f32x16 acc[2][2];
#pragma unroll
    for (int mi = 0; mi < 2; ++mi)
#pragma unroll
        for (int ni = 0; ni < 2; ++ni)
#pragma unroll
            for (int q = 0; q < 16; ++q) acc[mi][ni][q] = 0.f;

    const int wrow = (wv >> 1) * 64, wcol = (wv & 1) * 64;
    const int fl = l & 31, fh = l >> 5;
    const int rswz = (fl & 7) ^ ((fl & 8) >> 1);   // swz(row) for frag reads

    STAGE(0, 0);
    __syncthreads();
    int cur = 0;
    for (int kt = 0; kt < 8; ++kt) {
        if (kt < 7) STAGE(cur ^ 1, (kt + 1) * 64);
#pragma unroll
        for (int ks = 0; ks < 4; ++ks) {
            const int g  = ks * 2 + fh;
            const int cc = (g ^ rswz) * 8;
            const bf16x8 a0 = *(const bf16x8*)&As[cur][wrow + fl][cc];
            const bf16x8 a1 = *(const bf16x8*)&As[cur][wrow + 32 + fl][cc];
            const bf16x8 b0 = *(const bf16x8*)&Bs[cur][wcol + fl][cc];
            const bf16x8 b1 = *(const bf16x8*)&Bs[cur][wcol + 32 + fl][cc];
            acc[0][0] = __builtin_amdgcn_mfma_f32_32x32x16_bf16(a0, b0, acc[0][0], 0, 0, 0);
            acc[0][1] = __builtin_amdgcn_mfma_f32_32x32x16_bf16(a0, b1, acc[0][1], 0, 0, 0);
            acc[1][0] = __builtin_amdgcn_mfma_f32_32x32x16_bf16(a1, b0, acc[1][0], 0, 0, 0);
            acc[1][1] = __builtin_amdgcn_mfma_f32_32x32x16_bf16(a1, b1, acc[1][1], 0, 0, 0);
        }
        __syncthreads();
        cur ^= 1;
    }
#undef STAGE

    // epilogue: 32x32 C/D layout col = lane&31, row = (reg&3) + 8*(reg>>2) + 4*(lane>>5)
    const int crow_base = 4 * fh;
#pragma unroll
    for (int ni = 0; ni < 2; ++ni) {
        const int col = ct * 128 + wcol + ni * 32 + fl;
        const bool cok = (col < PRED);
        const float ebv = cok ? eb[e * PRED + col] : 0.f;
#pragma unroll
        for (int mi = 0; mi < 2; ++mi) {
#pragma unroll
            for (int q = 0; q < 16; ++q) {
                const int rl = wrow + mi * 32 + (q & 3) + 8 * (q >> 2) + crow_base;
                const int bb = rowB[rl];
                if (!cok || bb < 0) continue;
                const float v = acc[mi][ni][q] + ebv;
                float* op = out + (size_t)bb * PRED + col;
                if (SLOT == 0) *op = rowMu[rl] + rowC[rl] * v;
                else           *op += rowC[rl] * v;
            }
        }
    }
}

// -------------------------------- launch ---------------------------------------------
extern "C" void kernel_launch(void* const* d_in, const int* in_sizes, int n_in,
                              void* d_out, int out_size, void* d_ws, size_t ws_size,
                              hipStream_t stream)
{
    const float* x  = (const float*)d_in[0];
    const float* gw = (const float*)d_in[1];
    const float* gb = (const float*)d_in[2];
    const float* ew = (const float*)d_in[3];
    const float* eb = (const float*)d_in[4];
    float* out = (float*)d_out;
    char*  ws  = (char*)d_ws;

    constexpr size_t XN_OFF   = 0;
    constexpr size_t XN_SZ    = (size_t)NROWS * SEQ * 2;
    constexpr size_t EWT_OFF  = XN_OFF + XN_SZ;
    constexpr size_t EWT_SZ   = (size_t)NEXP * PRED * SEQ * 2;
    constexpr size_t META_OFF = EWT_OFF + EWT_SZ;
    constexpr size_t META_SZ  = (size_t)NROWS * 4 * 4;
    constexpr size_t EIDX_OFF = META_OFF + META_SZ;
    constexpr size_t EIDX_SZ  = (size_t)NROWS * 2 * 4;
    constexpr size_t LIST_OFF = EIDX_OFF + EIDX_SZ;
    constexpr size_t LIST_SZ  = (size_t)2 * NROWS * 4;
    constexpr size_t CNT_OFF  = LIST_OFF + LIST_SZ;
    constexpr size_t OFFS_OFF = CNT_OFF + 128;
    constexpr size_t CURS_OFF = OFFS_OFF + 128;
    constexpr size_t TOFF_OFF = CURS_OFF + 128;

    __hip_bfloat16* xn  = (__hip_bfloat16*)(ws + XN_OFF);
    __hip_bfloat16* ewt = (__hip_bfloat16*)(ws + EWT_OFF);
    float* meta  = (float*)(ws + META_OFF);
    int* eidx    = (int*)(ws + EIDX_OFF);
    int* lists   = (int*)(ws + LIST_OFF);
    int* counts  = (int*)(ws + CNT_OFF);
    int* offs    = (int*)(ws + OFFS_OFF);
    int* cursors = (int*)(ws + CURS_OFF);
    int* toff    = (int*)(ws + TOFF_OFF);

    hipMemsetAsync(counts, 0, 128, stream);

    k_transpose_ew<<<dim3(23, 16, NEXP), dim3(256), 0, stream>>>(ew, ewt);
    k_gate<<<dim3(NROWS / 4), dim3(256), 0, stream>>>(x, gw, gb, xn, meta, eidx, counts);
    k_scan<<<dim3(1), dim3(64), 0, stream>>>(counts, offs, cursors, toff);
    k_scatter<<<dim3(NROWS / 256), dim3(256), 0, stream>>>(eidx, cursors, lists);
    k_expert_gemm<0><<<dim3(6, 80), dim3(256), 0, stream>>>(
        xn, ewt, eb, meta, lists, offs, counts, toff, out);
    k_expert_gemm<1><<<dim3(6, 80), dim3(256), 0, stream>>>(
        xn, ewt, eb, meta, lists, offs, counts, toff, out);
}